// Round 4
// baseline (159.155 us; speedup 1.0000x reference)
//
#include <hip/hip_runtime.h>
#include <math.h>

// Round 4 = Round 3 with the P-buffer stride bug fixed (PSTR 76 -> 136).
// k_theta fused into k_attn (conv hides chunk-0 load latency).
// S^T = K.Q^T operand order -> b64 P-writes; row-sums via ones-MFMA;
// 2-deep global->reg prefetch for K/V staging; scalar (SGPR) weights.

#define B_SZ 16
#define C_IN 64
#define C_INT 32
#define HW 4096
#define NKV 1024
#define CHK 128
#define NCHUNK 8
#define KSTR 40    // sK row stride (ushorts)
#define VSTR 136   // sVt row stride (ushorts)
#define PSTR 136   // sP row stride (ushorts): 128 kv cols + 8 pad  [R3 bug: was 76]
#define QSTR 36    // sQf / sy row stride (floats; 144 B rows, 16B-aligned)

typedef __attribute__((ext_vector_type(8))) short bfrag;
typedef __attribute__((ext_vector_type(4))) float f32x4;

static __device__ __forceinline__ ushort f2bf(float v) {
  union { float f; uint u; } c; c.f = v;
  uint b = c.u + 0x7FFFu + ((c.u >> 16) & 1u);
  return (ushort)(b >> 16);
}
static __device__ __forceinline__ float bf2f(ushort h) {
  union { uint u; float f; } c; c.u = (uint)h << 16; return c.f;
}

// -------- kernel 1: phi & origin conv + maxpool -> Khi/Klo, Vt --------
__global__ __launch_bounds__(256, 2) void k_kv(
    const float* __restrict__ x,
    const float* __restrict__ wphi, const float* __restrict__ bphi,
    const float* __restrict__ worg, const float* __restrict__ borg,
    ushort* __restrict__ Khi, ushort* __restrict__ Klo, ushort* __restrict__ Vt) {
  __shared__ float red[2][4][32][33];
  int t = threadIdx.x;
  int bb = blockIdx.x >> 5;
  int g  = blockIdx.x & 31;
  int sel = t >> 7;
  int sel_u = __builtin_amdgcn_readfirstlane(sel);   // wave-uniform -> SGPR weights
  const float* wsel = sel_u ? worg : wphi;
  const float* bsel = sel_u ? borg : bphi;
  int sub = t & 127;
  int d = sub >> 5, mp_off = sub & 31;
  int mp = g * 32 + mp_off;
  int py = mp >> 5, px = mp & 31;
  int pix = (py << 7) + (px << 1) + ((d >> 1) << 6) + (d & 1);
  const float* xp = x + ((size_t)bb << 18) + pix;
  float acc[C_INT];
  #pragma unroll
  for (int o = 0; o < C_INT; ++o) acc[o] = bsel[o];
  for (int cq = 0; cq < 16; ++cq) {
    float xv0 = xp[(size_t)(4*cq+0) << 12];
    float xv1 = xp[(size_t)(4*cq+1) << 12];
    float xv2 = xp[(size_t)(4*cq+2) << 12];
    float xv3 = xp[(size_t)(4*cq+3) << 12];
    #pragma unroll
    for (int o = 0; o < C_INT; ++o) {
      const float4 w4 = *(const float4*)&wsel[o * C_IN + 4*cq];   // s_load (uniform)
      acc[o] += xv0*w4.x + xv1*w4.y + xv2*w4.z + xv3*w4.w;
    }
  }
  #pragma unroll
  for (int o = 0; o < C_INT; ++o) red[sel][d][mp_off][o] = acc[o];
  __syncthreads();
  if (sel == 0) {
    for (int f = sub; f < 1024; f += 128) {
      int mo = f >> 5, o = f & 31;
      float v = fmaxf(fmaxf(red[0][0][mo][o], red[0][1][mo][o]),
                      fmaxf(red[0][2][mo][o], red[0][3][mo][o]));
      ushort hb = f2bf(v);
      size_t idx = ((size_t)bb * NKV + g * 32 + mo) * 32 + o;
      Khi[idx] = hb;
      Klo[idx] = f2bf(v - bf2f(hb));
    }
  } else {
    for (int f = sub; f < 1024; f += 128) {
      int o = f >> 5, mo = f & 31;
      float v = fmaxf(fmaxf(red[1][0][mo][o], red[1][1][mo][o]),
                      fmaxf(red[1][2][mo][o], red[1][3][mo][o]));
      Vt[((size_t)bb * 32 + o) * NKV + g * 32 + mo] = f2bf(v);
    }
  }
}

// -------- kernel 2: fused theta-conv + MFMA flash attention + W-conv --------
__global__ __launch_bounds__(256, 2) void k_attn(
    const float* __restrict__ x,
    const float* __restrict__ wT, const float* __restrict__ bT,
    const ushort* __restrict__ Khi, const ushort* __restrict__ Klo,
    const ushort* __restrict__ Vt,
    const float* __restrict__ wW, const float* __restrict__ bW,
    float* __restrict__ z) {
  __shared__ __align__(16) ushort sK[2][128 * KSTR];   // 20480 B; reused as sy (18432 B)
  __shared__ __align__(16) ushort sVt[32 * VSTR];      // 8704 B
  __shared__ __align__(16) ushort sPQ[4 * 32 * PSTR];  // 34816 B; reused as sQf (18432 B)

  int t = threadIdx.x;
  int wave = t >> 6, lane = t & 63, l15 = lane & 15, quad = lane >> 4;
  int bb = blockIdx.x >> 5;
  int p0 = (blockIdx.x & 31) << 7;

  const ushort* Kh_g = Khi + (size_t)bb * NKV * 32;
  const ushort* Kl_g = Klo + (size_t)bb * NKV * 32;
  const ushort* Vt_g = Vt  + (size_t)bb * 32 * NKV;

  uint4 rKh[2], rKl[2], rV[2];
  auto LOAD = [&](int c) {
    int k0 = c * CHK;
    #pragma unroll
    for (int i = 0; i < 2; ++i) {
      int idx = i * 256 + t;
      int row = idx >> 2, seg = idx & 3;
      rKh[i] = *(const uint4*)(Kh_g + (size_t)(k0 + row) * 32 + seg * 8);
      rKl[i] = *(const uint4*)(Kl_g + (size_t)(k0 + row) * 32 + seg * 8);
      int vrow = idx >> 4, vseg = idx & 15;
      rV[i] = *(const uint4*)(Vt_g + (size_t)vrow * NKV + k0 + vseg * 8);
    }
  };
  auto STORE = [&]() {
    #pragma unroll
    for (int i = 0; i < 2; ++i) {
      int idx = i * 256 + t;
      int row = idx >> 2, seg = idx & 3;
      *(uint4*)&sK[0][row * KSTR + seg * 8] = rKh[i];
      *(uint4*)&sK[1][row * KSTR + seg * 8] = rKl[i];
      int vrow = idx >> 4, vseg = idx & 15;
      *(uint4*)&sVt[vrow * VSTR + vseg * 8] = rV[i];
    }
  };

  LOAD(0);   // chunk-0 global loads in flight; conv below hides their latency

  // ---- fused theta conv: 128 pixels x 32 out-ch -> sQf (fp32)
  float* sQf = (float*)sPQ;
  {
    int pl = t & 127;
    int half = __builtin_amdgcn_readfirstlane(t >> 7);  // wave-uniform
    const float* xp = x + ((size_t)bb << 18) + p0 + pl;
    float acc[16];
    #pragma unroll
    for (int o = 0; o < 16; ++o) acc[o] = bT[half * 16 + o];
    for (int cq = 0; cq < 16; ++cq) {
      float xv0 = xp[(size_t)(4*cq+0) << 12];
      float xv1 = xp[(size_t)(4*cq+1) << 12];
      float xv2 = xp[(size_t)(4*cq+2) << 12];
      float xv3 = xp[(size_t)(4*cq+3) << 12];
      #pragma unroll
      for (int o = 0; o < 16; ++o) {
        const float4 w4 = *(const float4*)&wT[(half*16+o) * C_IN + 4*cq];  // s_load
        acc[o] += xv0*w4.x + xv1*w4.y + xv2*w4.z + xv3*w4.w;
      }
    }
    #pragma unroll
    for (int o4 = 0; o4 < 4; ++o4)
      *(float4*)&sQf[pl * QSTR + half * 16 + o4 * 4] =
          make_float4(acc[o4*4], acc[o4*4+1], acc[o4*4+2], acc[o4*4+3]);
  }
  __syncthreads();

  // ---- Q frags (B-operand layout B[k=quad*8+j][n=l15]), hi/lo split
  bfrag aQh[2], aQl[2];
  #pragma unroll
  for (int rt = 0; rt < 2; ++rt) {
    const float* qrow = &sQf[(wave * 32 + rt * 16 + l15) * QSTR + quad * 8];
    #pragma unroll
    for (int k = 0; k < 8; ++k) {
      float v = qrow[k];
      ushort hb = f2bf(v);
      aQh[rt][k] = (short)hb;
      aQl[rt][k] = (short)f2bf(v - bf2f(hb));
    }
  }
  __syncthreads();   // all waves done with sQf -> sP region reusable
  STORE();           // chunk 0 -> LDS
  __syncthreads();

  f32x4 accO[2][2], accS[2];
  #pragma unroll
  for (int i = 0; i < 2; ++i) {
    accS[i] = (f32x4){0.f,0.f,0.f,0.f};
    #pragma unroll
    for (int j = 0; j < 2; ++j) accO[i][j] = (f32x4){0.f,0.f,0.f,0.f};
  }
  bfrag vones;
  #pragma unroll
  for (int i = 0; i < 8; ++i) vones[i] = (short)0x3F80;  // bf16 1.0

  ushort* myP = sPQ + wave * 32 * PSTR;

  for (int c = 0; c < NCHUNK; ++c) {
    if (c + 1 < NCHUNK) LOAD(c + 1);   // prefetch next chunk (overlaps compute)

    // ---- S^T = K.Q^T : C-layout row = kv-col (quad*4+r), col = q-row (l15)
    #pragma unroll
    for (int tt = 0; tt < 8; ++tt) {
      bfrag kh = *(const bfrag*)&sK[0][(tt*16 + l15) * KSTR + quad * 8];
      bfrag kl = *(const bfrag*)&sK[1][(tt*16 + l15) * KSTR + quad * 8];
      #pragma unroll
      for (int qt = 0; qt < 2; ++qt) {
        f32x4 s = (f32x4){0.f,0.f,0.f,0.f};
        s = __builtin_amdgcn_mfma_f32_16x16x32_bf16(kh, aQh[qt], s, 0, 0, 0);
        s = __builtin_amdgcn_mfma_f32_16x16x32_bf16(kh, aQl[qt], s, 0, 0, 0);
        s = __builtin_amdgcn_mfma_f32_16x16x32_bf16(kl, aQh[qt], s, 0, 0, 0);
        float e0 = __expf(s[0]), e1 = __expf(s[1]);
        float e2 = __expf(s[2]), e3 = __expf(s[3]);
        uint2 pk;   // truncation to bf16: normalization cancels the bias
        pk.x = (__float_as_uint(e0) >> 16) | (__float_as_uint(e1) & 0xFFFF0000u);
        pk.y = (__float_as_uint(e2) >> 16) | (__float_as_uint(e3) & 0xFFFF0000u);
        *(uint2*)&myP[(qt*16 + l15) * PSTR + tt*16 + quad*4] = pk;  // b64 write
      }
    }

    // ---- O += P.V ; row-sums via ones-MFMA (lands in matching C-layout rows)
    #pragma unroll
    for (int ks = 0; ks < 4; ++ks) {
      bfrag a0 = *(const bfrag*)&myP[(0*16 + l15) * PSTR + ks*32 + quad*8];
      bfrag a1 = *(const bfrag*)&myP[(1*16 + l15) * PSTR + ks*32 + quad*8];
      bfrag b0 = *(const bfrag*)&sVt[l15 * VSTR + ks*32 + quad*8];
      bfrag b1 = *(const bfrag*)&sVt[(16 + l15) * VSTR + ks*32 + quad*8];
      accO[0][0] = __builtin_amdgcn_mfma_f32_16x16x32_bf16(a0, b0, accO[0][0], 0, 0, 0);
      accO[0][1] = __builtin_amdgcn_mfma_f32_16x16x32_bf16(a0, b1, accO[0][1], 0, 0, 0);
      accO[1][0] = __builtin_amdgcn_mfma_f32_16x16x32_bf16(a1, b0, accO[1][0], 0, 0, 0);
      accO[1][1] = __builtin_amdgcn_mfma_f32_16x16x32_bf16(a1, b1, accO[1][1], 0, 0, 0);
      accS[0]    = __builtin_amdgcn_mfma_f32_16x16x32_bf16(a0, vones, accS[0], 0, 0, 0);
      accS[1]    = __builtin_amdgcn_mfma_f32_16x16x32_bf16(a1, vones, accS[1], 0, 0, 0);
    }

    if (c + 1 < NCHUNK) {
      __syncthreads();   // all waves done reading chunk c
      STORE();           // chunk c+1 -> LDS (vmcnt drained long ago)
      __syncthreads();
    }
  }

  __syncthreads();   // everyone done with sK -> reuse as sy
  float* sy = (float*)sK;
  #pragma unroll
  for (int qt = 0; qt < 2; ++qt)
    #pragma unroll
    for (int r = 0; r < 4; ++r) {
      float inv = 1.0f / accS[qt][r];
      #pragma unroll
      for (int n = 0; n < 2; ++n)
        sy[(wave*32 + qt*16 + quad*4 + r) * QSTR + n*16 + l15] = accO[qt][n][r] * inv;
    }
  __syncthreads();

  // ---- z = W.y + bW + x (weights via s_load, uniform)
  {
    int pl = t & 127;
    int halfo = __builtin_amdgcn_readfirstlane(t >> 7);
    float yv[C_INT];
    #pragma unroll
    for (int c4 = 0; c4 < 8; ++c4) {
      float4 f = *(const float4*)&sy[pl * QSTR + c4 * 4];
      yv[c4*4+0] = f.x; yv[c4*4+1] = f.y; yv[c4*4+2] = f.z; yv[c4*4+3] = f.w;
    }
    #pragma unroll
    for (int co = 0; co < 32; ++co) {
      int cout = halfo * 32 + co;
      size_t zi = ((size_t)bb << 18) + ((size_t)cout << 12) + p0 + pl;
      float a = bW[cout] + x[zi];
      #pragma unroll
      for (int c4 = 0; c4 < 8; ++c4) {
        const float4 w4 = *(const float4*)&wW[cout * C_INT + c4 * 4];
        a += yv[c4*4+0]*w4.x + yv[c4*4+1]*w4.y + yv[c4*4+2]*w4.z + yv[c4*4+3]*w4.w;
      }
      z[zi] = a;
    }
  }
}

extern "C" void kernel_launch(void* const* d_in, const int* in_sizes, int n_in,
                              void* d_out, int out_size, void* d_ws, size_t ws_size,
                              hipStream_t stream) {
  const float* x   = (const float*)d_in[0];
  const float* w_o = (const float*)d_in[1];
  const float* b_o = (const float*)d_in[2];
  const float* w_t = (const float*)d_in[3];
  const float* b_t = (const float*)d_in[4];
  const float* w_p = (const float*)d_in[5];
  const float* b_p = (const float*)d_in[6];
  const float* w_W = (const float*)d_in[7];
  const float* b_W = (const float*)d_in[8];
  float* z = (float*)d_out;

  ushort* Khi = (ushort*)d_ws;                              // 16*1024*32
  ushort* Klo = Khi + (size_t)B_SZ * NKV * C_INT;
  ushort* Vtw = Klo + (size_t)B_SZ * NKV * C_INT;           // 16*32*1024

  k_kv<<<dim3(B_SZ * 32), dim3(256), 0, stream>>>(x, w_p, b_p, w_o, b_o, Khi, Klo, Vtw);
  k_attn<<<dim3(B_SZ * 32), dim3(256), 0, stream>>>(x, w_t, b_t, Khi, Klo, Vtw, w_W, b_W, z);
}